// Round 1
// baseline (152.212 us; speedup 1.0000x reference)
//
#include <hip/hip_runtime.h>

typedef unsigned short u16;
typedef unsigned int u32;
typedef __bf16 bf16x8 __attribute__((ext_vector_type(8)));
typedef float f32x4 __attribute__((ext_vector_type(4)));

#define B_ 4
#define S_ 2048
#define E_ 1024
#define H_ 16
#define D_ 64

__device__ __forceinline__ u16 f2bf(float f) {
  u32 u = __float_as_uint(f);
  u32 r = u + 0x7fffu + ((u >> 16) & 1u);
  return (u16)(r >> 16);
}

// ---------------- LayerNorm: x fp32 [8192,1024] -> xn bf16 ----------------
// one wave per row; float4 loads; wave shuffle reduce
__global__ __launch_bounds__(256) void ln_kernel(const float* __restrict__ x,
                                                 const float* __restrict__ w,
                                                 u16* __restrict__ xn) {
  const int lane = threadIdx.x & 63;
  const int wv = threadIdx.x >> 6;
  const int row = blockIdx.x * 4 + wv;
  const float4* xr = (const float4*)(x + (size_t)row * E_);
  float4 vv[4];
  float s = 0.f, sq = 0.f;
#pragma unroll
  for (int i = 0; i < 4; ++i) {
    vv[i] = xr[lane + i * 64];
    s += vv[i].x + vv[i].y + vv[i].z + vv[i].w;
    sq += vv[i].x * vv[i].x + vv[i].y * vv[i].y + vv[i].z * vv[i].z + vv[i].w * vv[i].w;
  }
#pragma unroll
  for (int off = 1; off < 64; off <<= 1) {
    s += __shfl_xor(s, off);
    sq += __shfl_xor(sq, off);
  }
  const float mu = s * (1.f / E_);
  const float rs = rsqrtf(sq * (1.f / E_) - mu * mu + 1e-5f);
  u16* xo = xn + (size_t)row * E_;
  const float4* wr = (const float4*)w;
#pragma unroll
  for (int i = 0; i < 4; ++i) {
    float4 w4 = wr[lane + i * 64];
    ushort4 o;
    o.x = f2bf((vv[i].x - mu) * rs * w4.x);
    o.y = f2bf((vv[i].y - mu) * rs * w4.y);
    o.z = f2bf((vv[i].z - mu) * rs * w4.z);
    o.w = f2bf((vv[i].w - mu) * rs * w4.w);
    ((ushort4*)xo)[lane + i * 64] = o;
  }
}

// ---------------- fp32 -> bf16 convert (exact grid, no tail) ----------------
__global__ __launch_bounds__(256) void cvt_kernel(const float* __restrict__ src,
                                                  u16* __restrict__ dst) {
  const int i = blockIdx.x * 256 + threadIdx.x;
  float4 v = ((const float4*)src)[i];
  ushort4 o;
  o.x = f2bf(v.x);
  o.y = f2bf(v.y);
  o.z = f2bf(v.z);
  o.w = f2bf(v.w);
  ((ushort4*)dst)[i] = o;
}

// ---------------- GEMM C[M,N] = A[M,K] * B[N,K]^T, bf16 in, fp32 acc -------
// 128x128 tile, BK=64, 4 waves (2x2), each wave 4x4 frags of 16x16x32 MFMA.
// LDS padded to stride 72 elements (144B) -> 2-way-max bank aliasing (free).
// EPI 0: scatter to q/k/v [B,H,S,D] bf16.  EPI 1: +residual, fp32 out.
template <int EPI>
__global__ __launch_bounds__(256) void gemm_bt(const u16* __restrict__ A,
                                               const u16* __restrict__ Bw,
                                               const int K,
                                               u16* __restrict__ qo, u16* __restrict__ ko,
                                               u16* __restrict__ vo,
                                               const float* __restrict__ xres,
                                               float* __restrict__ outp) {
  __shared__ u16 As[128 * 72];
  __shared__ u16 Bs[128 * 72];
  const int t = threadIdx.x;
  const int lane = t & 63, wv = t >> 6;
  const int wm = wv >> 1, wn = wv & 1;
  const int m0 = blockIdx.y * 128, n0 = blockIdx.x * 128;
  const int r16 = lane & 15, g4 = lane >> 4;

  const f32x4 fzero = {0.f, 0.f, 0.f, 0.f};
  f32x4 acc[4][4];
#pragma unroll
  for (int i = 0; i < 4; ++i)
#pragma unroll
    for (int j = 0; j < 4; ++j) acc[i][j] = fzero;

  const int srow = t >> 3;        // 0..31
  const int scol = (t & 7) * 8;   // 0..56 (16B chunks)

  for (int kt = 0; kt < K; kt += 64) {
    uint4 va[4], vb[4];
#pragma unroll
    for (int i = 0; i < 4; ++i) {
      const int row = srow + i * 32;
      va[i] = *(const uint4*)(A + (size_t)(m0 + row) * K + kt + scol);
      vb[i] = *(const uint4*)(Bw + (size_t)(n0 + row) * K + kt + scol);
    }
#pragma unroll
    for (int i = 0; i < 4; ++i) {
      const int row = srow + i * 32;
      *(uint4*)&As[row * 72 + scol] = va[i];
      *(uint4*)&Bs[row * 72 + scol] = vb[i];
    }
    __syncthreads();
    bf16x8 af[4][2], bf2[4][2];
#pragma unroll
    for (int mi = 0; mi < 4; ++mi)
#pragma unroll
      for (int kc = 0; kc < 2; ++kc)
        af[mi][kc] = *(const bf16x8*)&As[(wm * 64 + mi * 16 + r16) * 72 + kc * 32 + g4 * 8];
#pragma unroll
    for (int ni = 0; ni < 4; ++ni)
#pragma unroll
      for (int kc = 0; kc < 2; ++kc)
        bf2[ni][kc] = *(const bf16x8*)&Bs[(wn * 64 + ni * 16 + r16) * 72 + kc * 32 + g4 * 8];
#pragma unroll
    for (int mi = 0; mi < 4; ++mi)
#pragma unroll
      for (int ni = 0; ni < 4; ++ni)
#pragma unroll
        for (int kc = 0; kc < 2; ++kc)
          acc[mi][ni] = __builtin_amdgcn_mfma_f32_16x16x32_bf16(af[mi][kc], bf2[ni][kc],
                                                                acc[mi][ni], 0, 0, 0);
    __syncthreads();
  }

  if constexpr (EPI == 0) {
    // scatter qkv: col f in [0,3072): which=f>>10, h=(f>>6)&15, d=f&63
#pragma unroll
    for (int mi = 0; mi < 4; ++mi)
#pragma unroll
      for (int e = 0; e < 4; ++e) {
        const int gr = m0 + wm * 64 + mi * 16 + g4 * 4 + e;
        const int bb = gr >> 11, ss = gr & 2047;
#pragma unroll
        for (int ni = 0; ni < 4; ++ni) {
          const int gc = n0 + wn * 64 + ni * 16 + r16;
          const int which = gc >> 10;
          const int hh = (gc >> 6) & 15;
          const int dd = gc & 63;
          u16* dst = which == 0 ? qo : (which == 1 ? ko : vo);
          dst[(((size_t)bb * H_ + hh) * S_ + ss) * D_ + dd] = f2bf(acc[mi][ni][e]);
        }
      }
  } else {
#pragma unroll
    for (int mi = 0; mi < 4; ++mi)
#pragma unroll
      for (int e = 0; e < 4; ++e) {
        const int gr = m0 + wm * 64 + mi * 16 + g4 * 4 + e;
#pragma unroll
        for (int ni = 0; ni < 4; ++ni) {
          const int gc = n0 + wn * 64 + ni * 16 + r16;
          const size_t idx = (size_t)gr * 1024 + gc;
          outp[idx] = acc[mi][ni][e] + xres[idx];
        }
      }
  }
}

// ---------------- windowed causal flash attention -------------------------
// grid(32, 64): x = Q-tile index (64 rows), y = b*H+h. block = 256 (4 waves x 16 rows)
// bias slope*(j-i), j<=i. slope=softplus(100*scaler). Window: tiles where the
// bias hasn't underflowed (exact vs fp32 reference; falls back to full causal).
__global__ __launch_bounds__(256) void attn_kernel(const u16* __restrict__ q,
                                                   const u16* __restrict__ k,
                                                   const u16* __restrict__ v,
                                                   const float* __restrict__ scaler_p,
                                                   u16* __restrict__ ao) {
  __shared__ u16 Qs[64 * 72];
  __shared__ u16 Ks[64 * 72];
  __shared__ u16 Vt[64 * 72];
  __shared__ u16 Ps[4 * 16 * 72];
  const int t = threadIdx.x;
  const int lane = t & 63, wv = t >> 6;
  const int r16 = lane & 15, g4 = lane >> 4;
  const int it = blockIdx.x;
  const int bh = blockIdx.y;
  const int bb = bh >> 4, hh = bh & 15;
  const size_t base = (size_t)bh * (S_ * D_);

  const float tt = 100.f * scaler_p[0];
  const float slope = (tt > 20.f) ? tt : log1pf(expf(tt));
  const float L2E = 1.4426950408889634f;
  const float qs_l2e = 0.125f * L2E;  // 1/sqrt(64) * log2(e)
  const float sl_l2e = slope * L2E;
  int nb = (int)ceilf(80.f / (slope * 64.f));
  if (nb < 1) nb = 1;
  int jt0 = it - nb;
  if (jt0 < 0) jt0 = 0;

  // stage Q tile [64][72]
  {
    const int r = t >> 2, c = (t & 3) << 4;
    const u16* gp = q + base + (size_t)(it * 64 + r) * D_ + c;
    uint4 a0 = ((const uint4*)gp)[0];
    uint4 a1 = ((const uint4*)gp)[1];
    *(uint4*)&Qs[r * 72 + c] = a0;
    *(uint4*)&Qs[r * 72 + c + 8] = a1;
  }

  float mrun[4] = {-3e38f, -3e38f, -3e38f, -3e38f};
  float lrun[4] = {0.f, 0.f, 0.f, 0.f};
  const f32x4 fzero = {0.f, 0.f, 0.f, 0.f};
  f32x4 oacc[4];
#pragma unroll
  for (int i = 0; i < 4; ++i) oacc[i] = fzero;

  bf16x8 qa[2];
  bool qloaded = false;

  for (int jt = jt0; jt <= it; ++jt) {
    // stage K [64][72] and V^T [64 d][72 s]
    {
      const int r = t >> 2, c = (t & 3) << 4;
      const u16* kg = k + base + (size_t)(jt * 64 + r) * D_ + c;
      uint4 k0 = ((const uint4*)kg)[0];
      uint4 k1 = ((const uint4*)kg)[1];
      *(uint4*)&Ks[r * 72 + c] = k0;
      *(uint4*)&Ks[r * 72 + c + 8] = k1;
      const u16* vg = v + base + (size_t)(jt * 64 + r) * D_ + c;
      union { uint4 u; u16 s[8]; } v0, v1;
      v0.u = ((const uint4*)vg)[0];
      v1.u = ((const uint4*)vg)[1];
#pragma unroll
      for (int j = 0; j < 8; ++j) {
        Vt[(c + j) * 72 + r] = v0.s[j];
        Vt[(c + 8 + j) * 72 + r] = v1.s[j];
      }
    }
    __syncthreads();
    if (!qloaded) {
      qloaded = true;
#pragma unroll
      for (int kc = 0; kc < 2; ++kc)
        qa[kc] = *(const bf16x8*)&Qs[(wv * 16 + r16) * 72 + kc * 32 + g4 * 8];
    }
    // S = Q K^T  (wave: 16 rows x 64 cols)
    f32x4 sfr[4];
#pragma unroll
    for (int nt = 0; nt < 4; ++nt) {
      sfr[nt] = fzero;
#pragma unroll
      for (int kc = 0; kc < 2; ++kc) {
        bf16x8 kb = *(const bf16x8*)&Ks[(nt * 16 + r16) * 72 + kc * 32 + g4 * 8];
        sfr[nt] = __builtin_amdgcn_mfma_f32_16x16x32_bf16(qa[kc], kb, sfr[nt], 0, 0, 0);
      }
    }
    // bias + mask + row max (exp2 domain)
    const bool diag = (jt == it);
    const float jb = (float)((jt - it) * 64);
    float pm[4] = {-3e38f, -3e38f, -3e38f, -3e38f};
#pragma unroll
    for (int nt = 0; nt < 4; ++nt) {
      const int jl = nt * 16 + r16;
#pragma unroll
      for (int e = 0; e < 4; ++e) {
        const int il = wv * 16 + g4 * 4 + e;
        float sc = sfr[nt][e] * qs_l2e + sl_l2e * (jb + (float)(jl - il));
        if (diag && jl > il) sc = -3e38f;
        sfr[nt][e] = sc;
        pm[e] = fmaxf(pm[e], sc);
      }
    }
#pragma unroll
    for (int e = 0; e < 4; ++e) {
#pragma unroll
      for (int off = 1; off < 16; off <<= 1) pm[e] = fmaxf(pm[e], __shfl_xor(pm[e], off));
    }
    // online softmax update
    u16* Psw = Ps + wv * (16 * 72);
    float psum[4] = {0.f, 0.f, 0.f, 0.f};
#pragma unroll
    for (int e = 0; e < 4; ++e) {
      const float mn = fmaxf(mrun[e], pm[e]);
      const float rsc = exp2f(mrun[e] - mn);
      mrun[e] = mn;
      lrun[e] *= rsc;
#pragma unroll
      for (int nt = 0; nt < 4; ++nt) oacc[nt][e] *= rsc;
    }
#pragma unroll
    for (int nt = 0; nt < 4; ++nt)
#pragma unroll
      for (int e = 0; e < 4; ++e) {
        const float p = exp2f(sfr[nt][e] - mrun[e]);
        psum[e] += p;
        Psw[(g4 * 4 + e) * 72 + nt * 16 + r16] = f2bf(p);
      }
#pragma unroll
    for (int e = 0; e < 4; ++e) {
#pragma unroll
      for (int off = 1; off < 16; off <<= 1) psum[e] += __shfl_xor(psum[e], off);
      lrun[e] += psum[e];
    }
    // O += P V
    bf16x8 pa[2];
#pragma unroll
    for (int jk = 0; jk < 2; ++jk)
      pa[jk] = *(const bf16x8*)&Psw[r16 * 72 + jk * 32 + g4 * 8];
#pragma unroll
    for (int nt = 0; nt < 4; ++nt)
#pragma unroll
      for (int jk = 0; jk < 2; ++jk) {
        bf16x8 vb = *(const bf16x8*)&Vt[(nt * 16 + r16) * 72 + jk * 32 + g4 * 8];
        oacc[nt] = __builtin_amdgcn_mfma_f32_16x16x32_bf16(pa[jk], vb, oacc[nt], 0, 0, 0);
      }
    __syncthreads();
  }
  // write attn out bf16 [B,S,E]
#pragma unroll
  for (int e = 0; e < 4; ++e) {
    const float inv = 1.f / lrun[e];
    const int row = it * 64 + wv * 16 + g4 * 4 + e;
#pragma unroll
    for (int nt = 0; nt < 4; ++nt) {
      const int col = hh * 64 + nt * 16 + r16;
      ao[((size_t)bb * S_ + row) * E_ + col] = f2bf(oacc[nt][e] * inv);
    }
  }
}

extern "C" void kernel_launch(void* const* d_in, const int* in_sizes, int n_in,
                              void* d_out, int out_size, void* d_ws, size_t ws_size,
                              hipStream_t stream) {
  const float* x = (const float*)d_in[0];
  const float* Wqkv = (const float*)d_in[1];
  const float* Wo = (const float*)d_in[2];
  const float* lnw = (const float*)d_in[3];
  const float* scaler = (const float*)d_in[4];
  float* out = (float*)d_out;
  char* ws = (char*)d_ws;

  // workspace layout (bytes)
  u16* xn = (u16*)(ws + 0);            // 16,777,216
  u16* q = (u16*)(ws + 16777216);      // 16,777,216
  u16* kk = (u16*)(ws + 33554432);     // 16,777,216
  u16* vv = (u16*)(ws + 50331648);     // 16,777,216
  u16* ao = (u16*)(ws + 67108864);     // 16,777,216
  u16* wqkvb = (u16*)(ws + 83886080);  // 6,291,456
  u16* wob = (u16*)(ws + 90177536);    // 2,097,152  -> total 92,274,688

  ln_kernel<<<2048, 256, 0, stream>>>(x, lnw, xn);
  cvt_kernel<<<3072, 256, 0, stream>>>(Wqkv, wqkvb);
  cvt_kernel<<<1024, 256, 0, stream>>>(Wo, wob);
  gemm_bt<0><<<dim3(24, 64), 256, 0, stream>>>(xn, wqkvb, 1024, q, kk, vv, nullptr, nullptr);
  attn_kernel<<<dim3(32, 64), 256, 0, stream>>>(q, kk, vv, scaler, ao);
  gemm_bt<1><<<dim3(8, 64), 256, 0, stream>>>(ao, wob, 1024, nullptr, nullptr, nullptr, x, out);
}

// Round 2
// 141.454 us; speedup vs baseline: 1.0761x; 1.0761x over previous
//
#include <hip/hip_runtime.h>

typedef unsigned short u16;
typedef unsigned int u32;
typedef __bf16 bf16x8 __attribute__((ext_vector_type(8)));
typedef float f32x4 __attribute__((ext_vector_type(4)));

#define B_ 4
#define S_ 2048
#define E_ 1024
#define H_ 16
#define D_ 64

__device__ __forceinline__ u16 f2bf(float f) {
  u32 u = __float_as_uint(f);
  u32 r = u + 0x7fffu + ((u >> 16) & 1u);
  return (u16)(r >> 16);
}

// async global->LDS, 16B per lane. dest = wave-uniform base + lane*16.
__device__ __forceinline__ void gload16(const u16* g, u16* l) {
  __builtin_amdgcn_global_load_lds((const __attribute__((address_space(1))) void*)g,
                                   (__attribute__((address_space(3))) void*)l, 16, 0, 0);
}

// ---------------- LayerNorm: x fp32 [8192,1024] -> xn bf16 ----------------
__global__ __launch_bounds__(256) void ln_kernel(const float* __restrict__ x,
                                                 const float* __restrict__ w,
                                                 u16* __restrict__ xn) {
  const int lane = threadIdx.x & 63;
  const int wv = threadIdx.x >> 6;
  const int row = blockIdx.x * 4 + wv;
  const float4* xr = (const float4*)(x + (size_t)row * E_);
  float4 vv[4];
  float s = 0.f, sq = 0.f;
#pragma unroll
  for (int i = 0; i < 4; ++i) {
    vv[i] = xr[lane + i * 64];
    s += vv[i].x + vv[i].y + vv[i].z + vv[i].w;
    sq += vv[i].x * vv[i].x + vv[i].y * vv[i].y + vv[i].z * vv[i].z + vv[i].w * vv[i].w;
  }
#pragma unroll
  for (int off = 1; off < 64; off <<= 1) {
    s += __shfl_xor(s, off);
    sq += __shfl_xor(sq, off);
  }
  const float mu = s * (1.f / E_);
  const float rs = rsqrtf(sq * (1.f / E_) - mu * mu + 1e-5f);
  u16* xo = xn + (size_t)row * E_;
  const float4* wr = (const float4*)w;
#pragma unroll
  for (int i = 0; i < 4; ++i) {
    float4 w4 = wr[lane + i * 64];
    ushort4 o;
    o.x = f2bf((vv[i].x - mu) * rs * w4.x);
    o.y = f2bf((vv[i].y - mu) * rs * w4.y);
    o.z = f2bf((vv[i].z - mu) * rs * w4.z);
    o.w = f2bf((vv[i].w - mu) * rs * w4.w);
    ((ushort4*)xo)[lane + i * 64] = o;
  }
}

// ---------------- fp32 -> bf16 convert ----------------
__global__ __launch_bounds__(256) void cvt_kernel(const float* __restrict__ src,
                                                  u16* __restrict__ dst) {
  const int i = blockIdx.x * 256 + threadIdx.x;
  float4 v = ((const float4*)src)[i];
  ushort4 o;
  o.x = f2bf(v.x);
  o.y = f2bf(v.y);
  o.z = f2bf(v.z);
  o.w = f2bf(v.w);
  ((ushort4*)dst)[i] = o;
}

// ---------------- GEMM C[M,N] = A[M,K] * B[N,K]^T, bf16 in, fp32 acc -------
// 128x128 tile, BK=64, 4 waves (2x2), each wave 64x64 (4x4 frags 16x16x32).
// T3-minimum 2-phase: global_load_lds(16B) double-buffered, one barrier/tile.
// LDS linear [128][64] per matrix (gload_lds needs linear dest).
template <int EPI>
__global__ __launch_bounds__(256, 2) void gemm_bt(const u16* __restrict__ A,
                                                  const u16* __restrict__ Bw,
                                                  const int K,
                                                  u16* __restrict__ qo, u16* __restrict__ ko,
                                                  u16* __restrict__ vo,
                                                  const float* __restrict__ xres,
                                                  float* __restrict__ outp) {
  __shared__ u16 lds[2][2][128 * 64];  // [buf][A/B][row*64+col] = 64 KiB
  const int t = threadIdx.x;
  const int lane = t & 63, wv = t >> 6;
  const int wm = wv >> 1, wn = wv & 1;
  const int m0 = blockIdx.y * 128, n0 = blockIdx.x * 128;
  const int r16 = lane & 15, g4 = lane >> 4;

  const f32x4 fzero = {0.f, 0.f, 0.f, 0.f};
  f32x4 acc[4][4];
#pragma unroll
  for (int i = 0; i < 4; ++i)
#pragma unroll
    for (int j = 0; j < 4; ++j) acc[i][j] = fzero;

  const int srow8 = lane >> 3;      // 0..7 within 8-row chunk
  const int scol = (lane & 7) * 8;  // halfword col 0..56

  // stage one 128x64 A-tile + B-tile into buffer bu (8 gload_lds per wave)
  auto stage = [&](int bu, int kt) {
#pragma unroll
    for (int i = 0; i < 4; ++i) {
      const int c = wv * 4 + i;          // chunk 0..15 (8 rows each)
      const int row = c * 8 + srow8;
      gload16(A + (size_t)(m0 + row) * K + kt + scol, &lds[bu][0][c * 512]);
      gload16(Bw + (size_t)(n0 + row) * K + kt + scol, &lds[bu][1][c * 512]);
    }
  };

  auto compute = [&](int bu) {
    const u16* As = lds[bu][0];
    const u16* Bs = lds[bu][1];
    bf16x8 af[4][2], bfr[4][2];
#pragma unroll
    for (int mi = 0; mi < 4; ++mi)
#pragma unroll
      for (int kc = 0; kc < 2; ++kc)
        af[mi][kc] = *(const bf16x8*)&As[(wm * 64 + mi * 16 + r16) * 64 + kc * 32 + g4 * 8];
#pragma unroll
    for (int ni = 0; ni < 4; ++ni)
#pragma unroll
      for (int kc = 0; kc < 2; ++kc)
        bfr[ni][kc] = *(const bf16x8*)&Bs[(wn * 64 + ni * 16 + r16) * 64 + kc * 32 + g4 * 8];
#pragma unroll
    for (int mi = 0; mi < 4; ++mi)
#pragma unroll
      for (int ni = 0; ni < 4; ++ni)
#pragma unroll
        for (int kc = 0; kc < 2; ++kc)
          acc[mi][ni] = __builtin_amdgcn_mfma_f32_16x16x32_bf16(af[mi][kc], bfr[ni][kc],
                                                                acc[mi][ni], 0, 0, 0);
  };

  stage(0, 0);
  __syncthreads();  // compiler drains vmcnt(0) before s_barrier
  int cur = 0;
  for (int kt = 64; kt < K; kt += 64) {
    stage(cur ^ 1, kt);  // prefetch next tile while computing current
    compute(cur);
    __syncthreads();
    cur ^= 1;
  }
  compute(cur);

  if constexpr (EPI == 0) {
    // scatter qkv: block's 128-col range lies entirely in one of q/k/v
    const int which = n0 >> 10;
    u16* dst = which == 0 ? qo : (which == 1 ? ko : vo);
#pragma unroll
    for (int mi = 0; mi < 4; ++mi)
#pragma unroll
      for (int e = 0; e < 4; ++e) {
        const int gr = m0 + wm * 64 + mi * 16 + g4 * 4 + e;
        const int bb = gr >> 11, ss = gr & 2047;
#pragma unroll
        for (int ni = 0; ni < 4; ++ni) {
          const int gc = n0 + wn * 64 + ni * 16 + r16;
          const int hh = (gc >> 6) & 15;
          const int dd = gc & 63;
          dst[(((size_t)bb * H_ + hh) * S_ + ss) * D_ + dd] = f2bf(acc[mi][ni][e]);
        }
      }
  } else {
#pragma unroll
    for (int mi = 0; mi < 4; ++mi)
#pragma unroll
      for (int e = 0; e < 4; ++e) {
        const int gr = m0 + wm * 64 + mi * 16 + g4 * 4 + e;
#pragma unroll
        for (int ni = 0; ni < 4; ++ni) {
          const int gc = n0 + wn * 64 + ni * 16 + r16;
          const size_t idx = (size_t)gr * 1024 + gc;
          outp[idx] = acc[mi][ni][e] + xres[idx];
        }
      }
  }
}

// ---------------- windowed causal flash attention (unchanged) -------------
__global__ __launch_bounds__(256) void attn_kernel(const u16* __restrict__ q,
                                                   const u16* __restrict__ k,
                                                   const u16* __restrict__ v,
                                                   const float* __restrict__ scaler_p,
                                                   u16* __restrict__ ao) {
  __shared__ u16 Qs[64 * 72];
  __shared__ u16 Ks[64 * 72];
  __shared__ u16 Vt[64 * 72];
  __shared__ u16 Ps[4 * 16 * 72];
  const int t = threadIdx.x;
  const int lane = t & 63, wv = t >> 6;
  const int r16 = lane & 15, g4 = lane >> 4;
  const int it = blockIdx.x;
  const int bh = blockIdx.y;
  const int bb = bh >> 4, hh = bh & 15;
  const size_t base = (size_t)bh * (S_ * D_);

  const float tt = 100.f * scaler_p[0];
  const float slope = (tt > 20.f) ? tt : log1pf(expf(tt));
  const float L2E = 1.4426950408889634f;
  const float qs_l2e = 0.125f * L2E;
  const float sl_l2e = slope * L2E;
  int nb = (int)ceilf(80.f / (slope * 64.f));
  if (nb < 1) nb = 1;
  int jt0 = it - nb;
  if (jt0 < 0) jt0 = 0;

  {
    const int r = t >> 2, c = (t & 3) << 4;
    const u16* gp = q + base + (size_t)(it * 64 + r) * D_ + c;
    uint4 a0 = ((const uint4*)gp)[0];
    uint4 a1 = ((const uint4*)gp)[1];
    *(uint4*)&Qs[r * 72 + c] = a0;
    *(uint4*)&Qs[r * 72 + c + 8] = a1;
  }

  float mrun[4] = {-3e38f, -3e38f, -3e38f, -3e38f};
  float lrun[4] = {0.f, 0.f, 0.f, 0.f};
  const f32x4 fzero = {0.f, 0.f, 0.f, 0.f};
  f32x4 oacc[4];
#pragma unroll
  for (int i = 0; i < 4; ++i) oacc[i] = fzero;

  bf16x8 qa[2];
  bool qloaded = false;

  for (int jt = jt0; jt <= it; ++jt) {
    {
      const int r = t >> 2, c = (t & 3) << 4;
      const u16* kg = k + base + (size_t)(jt * 64 + r) * D_ + c;
      uint4 k0 = ((const uint4*)kg)[0];
      uint4 k1 = ((const uint4*)kg)[1];
      *(uint4*)&Ks[r * 72 + c] = k0;
      *(uint4*)&Ks[r * 72 + c + 8] = k1;
      const u16* vg = v + base + (size_t)(jt * 64 + r) * D_ + c;
      union { uint4 u; u16 s[8]; } v0, v1;
      v0.u = ((const uint4*)vg)[0];
      v1.u = ((const uint4*)vg)[1];
#pragma unroll
      for (int j = 0; j < 8; ++j) {
        Vt[(c + j) * 72 + r] = v0.s[j];
        Vt[(c + 8 + j) * 72 + r] = v1.s[j];
      }
    }
    __syncthreads();
    if (!qloaded) {
      qloaded = true;
#pragma unroll
      for (int kc = 0; kc < 2; ++kc)
        qa[kc] = *(const bf16x8*)&Qs[(wv * 16 + r16) * 72 + kc * 32 + g4 * 8];
    }
    f32x4 sfr[4];
#pragma unroll
    for (int nt = 0; nt < 4; ++nt) {
      sfr[nt] = fzero;
#pragma unroll
      for (int kc = 0; kc < 2; ++kc) {
        bf16x8 kb = *(const bf16x8*)&Ks[(nt * 16 + r16) * 72 + kc * 32 + g4 * 8];
        sfr[nt] = __builtin_amdgcn_mfma_f32_16x16x32_bf16(qa[kc], kb, sfr[nt], 0, 0, 0);
      }
    }
    const bool diag = (jt == it);
    const float jb = (float)((jt - it) * 64);
    float pm[4] = {-3e38f, -3e38f, -3e38f, -3e38f};
#pragma unroll
    for (int nt = 0; nt < 4; ++nt) {
      const int jl = nt * 16 + r16;
#pragma unroll
      for (int e = 0; e < 4; ++e) {
        const int il = wv * 16 + g4 * 4 + e;
        float sc = sfr[nt][e] * qs_l2e + sl_l2e * (jb + (float)(jl - il));
        if (diag && jl > il) sc = -3e38f;
        sfr[nt][e] = sc;
        pm[e] = fmaxf(pm[e], sc);
      }
    }
#pragma unroll
    for (int e = 0; e < 4; ++e) {
#pragma unroll
      for (int off = 1; off < 16; off <<= 1) pm[e] = fmaxf(pm[e], __shfl_xor(pm[e], off));
    }
    u16* Psw = Ps + wv * (16 * 72);
    float psum[4] = {0.f, 0.f, 0.f, 0.f};
#pragma unroll
    for (int e = 0; e < 4; ++e) {
      const float mn = fmaxf(mrun[e], pm[e]);
      const float rsc = exp2f(mrun[e] - mn);
      mrun[e] = mn;
      lrun[e] *= rsc;
#pragma unroll
      for (int nt = 0; nt < 4; ++nt) oacc[nt][e] *= rsc;
    }
#pragma unroll
    for (int nt = 0; nt < 4; ++nt)
#pragma unroll
      for (int e = 0; e < 4; ++e) {
        const float p = exp2f(sfr[nt][e] - mrun[e]);
        psum[e] += p;
        Psw[(g4 * 4 + e) * 72 + nt * 16 + r16] = f2bf(p);
      }
#pragma unroll
    for (int e = 0; e < 4; ++e) {
#pragma unroll
      for (int off = 1; off < 16; off <<= 1) psum[e] += __shfl_xor(psum[e], off);
      lrun[e] += psum[e];
    }
    bf16x8 pa[2];
#pragma unroll
    for (int jk = 0; jk < 2; ++jk)
      pa[jk] = *(const bf16x8*)&Psw[r16 * 72 + jk * 32 + g4 * 8];
#pragma unroll
    for (int nt = 0; nt < 4; ++nt)
#pragma unroll
      for (int jk = 0; jk < 2; ++jk) {
        bf16x8 vb = *(const bf16x8*)&Vt[(nt * 16 + r16) * 72 + jk * 32 + g4 * 8];
        oacc[nt] = __builtin_amdgcn_mfma_f32_16x16x32_bf16(pa[jk], vb, oacc[nt], 0, 0, 0);
      }
    __syncthreads();
  }
#pragma unroll
  for (int e = 0; e < 4; ++e) {
    const float inv = 1.f / lrun[e];
    const int row = it * 64 + wv * 16 + g4 * 4 + e;
#pragma unroll
    for (int nt = 0; nt < 4; ++nt) {
      const int col = hh * 64 + nt * 16 + r16;
      ao[((size_t)bb * S_ + row) * E_ + col] = f2bf(oacc[nt][e] * inv);
    }
  }
}

extern "C" void kernel_launch(void* const* d_in, const int* in_sizes, int n_in,
                              void* d_out, int out_size, void* d_ws, size_t ws_size,
                              hipStream_t stream) {
  const float* x = (const float*)d_in[0];
  const float* Wqkv = (const float*)d_in[1];
  const float* Wo = (const float*)d_in[2];
  const float* lnw = (const float*)d_in[3];
  const float* scaler = (const float*)d_in[4];
  float* out = (float*)d_out;
  char* ws = (char*)d_ws;

  u16* xn = (u16*)(ws + 0);
  u16* q = (u16*)(ws + 16777216);
  u16* kk = (u16*)(ws + 33554432);
  u16* vv = (u16*)(ws + 50331648);
  u16* ao = (u16*)(ws + 67108864);
  u16* wqkvb = (u16*)(ws + 83886080);
  u16* wob = (u16*)(ws + 90177536);

  ln_kernel<<<2048, 256, 0, stream>>>(x, lnw, xn);
  cvt_kernel<<<3072, 256, 0, stream>>>(Wqkv, wqkvb);
  cvt_kernel<<<1024, 256, 0, stream>>>(Wo, wob);
  gemm_bt<0><<<dim3(24, 64), 256, 0, stream>>>(xn, wqkvb, 1024, q, kk, vv, nullptr, nullptr);
  attn_kernel<<<dim3(32, 64), 256, 0, stream>>>(q, kk, vv, scaler, ao);
  gemm_bt<1><<<dim3(8, 64), 256, 0, stream>>>(ao, wob, 1024, nullptr, nullptr, nullptr, x, out);
}

// Round 3
// 136.204 us; speedup vs baseline: 1.1175x; 1.0385x over previous
//
#include <hip/hip_runtime.h>

typedef unsigned short u16;
typedef unsigned int u32;
typedef __bf16 bf16x8 __attribute__((ext_vector_type(8)));
typedef float f32x4 __attribute__((ext_vector_type(4)));

#define B_ 4
#define S_ 2048
#define E_ 1024
#define H_ 16
#define D_ 64

__device__ __forceinline__ u16 f2bf(float f) {
  u32 u = __float_as_uint(f);
  u32 r = u + 0x7fffu + ((u >> 16) & 1u);
  return (u16)(r >> 16);
}

// async global->LDS, 16B per lane. LDS dest = wave-uniform base + lane*16.
__device__ __forceinline__ void gload16(const u16* g, u16* l) {
  __builtin_amdgcn_global_load_lds((const __attribute__((address_space(1))) void*)g,
                                   (__attribute__((address_space(3))) void*)l, 16, 0, 0);
}

// ---------------- LayerNorm: x fp32 [8192,1024] -> xn bf16 ----------------
__global__ __launch_bounds__(256) void ln_kernel(const float* __restrict__ x,
                                                 const float* __restrict__ w,
                                                 u16* __restrict__ xn) {
  const int lane = threadIdx.x & 63;
  const int wv = threadIdx.x >> 6;
  const int row = blockIdx.x * 4 + wv;
  const float4* xr = (const float4*)(x + (size_t)row * E_);
  float4 vv[4];
  float s = 0.f, sq = 0.f;
#pragma unroll
  for (int i = 0; i < 4; ++i) {
    vv[i] = xr[lane + i * 64];
    s += vv[i].x + vv[i].y + vv[i].z + vv[i].w;
    sq += vv[i].x * vv[i].x + vv[i].y * vv[i].y + vv[i].z * vv[i].z + vv[i].w * vv[i].w;
  }
#pragma unroll
  for (int off = 1; off < 64; off <<= 1) {
    s += __shfl_xor(s, off);
    sq += __shfl_xor(sq, off);
  }
  const float mu = s * (1.f / E_);
  const float rs = rsqrtf(sq * (1.f / E_) - mu * mu + 1e-5f);
  u16* xo = xn + (size_t)row * E_;
  const float4* wr = (const float4*)w;
#pragma unroll
  for (int i = 0; i < 4; ++i) {
    float4 w4 = wr[lane + i * 64];
    ushort4 o;
    o.x = f2bf((vv[i].x - mu) * rs * w4.x);
    o.y = f2bf((vv[i].y - mu) * rs * w4.y);
    o.z = f2bf((vv[i].z - mu) * rs * w4.z);
    o.w = f2bf((vv[i].w - mu) * rs * w4.w);
    ((ushort4*)xo)[lane + i * 64] = o;
  }
}

// ---------------- fp32 -> bf16 convert ----------------
__global__ __launch_bounds__(256) void cvt_kernel(const float* __restrict__ src,
                                                  u16* __restrict__ dst) {
  const int i = blockIdx.x * 256 + threadIdx.x;
  float4 v = ((const float4*)src)[i];
  ushort4 o;
  o.x = f2bf(v.x);
  o.y = f2bf(v.y);
  o.z = f2bf(v.z);
  o.w = f2bf(v.w);
  ((ushort4*)dst)[i] = o;
}

// =====================================================================
// 8-phase 256x256 GEMM  C[M,N] = A[M,K] * B[N,K]^T, bf16 in, fp32 acc.
// 512 thr = 8 waves (2M x 4N), per-wave 128x64 out, BK=64, LDS 128 KiB dbuf.
// T2 st-swizzle (hw ^= (row&7)<<3) via pre-swizzled global source + swizzled
// ds_read (rule #21). T3/T4: per-phase gload issue, vmcnt(6) steady,
// 4->2->0 epilogue drain. T5: setprio around MFMA cluster.
// Epilogue: scatter to q/k/v [B,H,S,D] bf16 (K fixed 1024).
// =====================================================================
__global__ __launch_bounds__(512, 2) void gemm8_qkv(const u16* __restrict__ A,
                                                    const u16* __restrict__ Bw,
                                                    u16* __restrict__ qo,
                                                    u16* __restrict__ ko,
                                                    u16* __restrict__ vo) {
  constexpr int K = 1024;
  constexpr int NT = K / 64;  // 16 K-tiles
  __shared__ u16 lds[2][2][256 * 64];  // [buf][A/B][row*64+hw] = 128 KiB
  const int t = threadIdx.x;
  const int lane = t & 63, wv = t >> 6;
  const int wm = wv >> 2, wn = wv & 3;
  const int m0 = blockIdx.y * 256, n0 = blockIdx.x * 256;
  const int r16 = lane & 15, g4 = lane >> 4;
  const int l3 = lane >> 3, l7 = lane & 7;
  const int colsrc = ((l7 ^ l3) * 8);  // inverse-swizzled source col (halfwords)

  f32x4 acc[8][4] = {};
  bf16x8 af[8][2];   // A frags: all 8 M-frags x 2 k-chunks (64 VGPR)
  bf16x8 bfr[2][2];  // B frags: current ni-pair x 2 k-chunks

  // stage group ph (0:Afirst 1:Blo 2:Asecond 3:Bhi) of K-slice kt into buf
  auto issue = [&](int ph, int buf, int kt) {
#pragma unroll
    for (int s = 0; s < 2; ++s) {
      const int j = wv * 2 + s;
      int c, m;
      if (ph == 0)      { m = 0; c = j + (j & 8); }
      else if (ph == 1) { m = 1; c = (j >> 2) * 8 + (j & 3); }
      else if (ph == 2) { m = 0; c = 8 + j + (j & 8); }
      else              { m = 1; c = (j >> 2) * 8 + 4 + (j & 3); }
      const u16* src = (m == 0 ? A + (size_t)(m0 + c * 8 + l3) * K
                               : Bw + (size_t)(n0 + c * 8 + l3) * K) + kt + colsrc;
      gload16(src, &lds[buf][m][c * 512]);
    }
  };

  auto loadA = [&](const u16* As, int half) {
#pragma unroll
    for (int i = 0; i < 4; ++i) {
      const int mi = half * 4 + i;
      const int r = wm * 128 + mi * 16 + r16;
      const int sw = (r & 7) << 3;
#pragma unroll
      for (int kc = 0; kc < 2; ++kc)
        af[mi][kc] = *(const bf16x8*)&As[r * 64 + ((kc * 32 + g4 * 8) ^ sw)];
    }
  };
  auto loadB = [&](const u16* Bs, int pair) {
#pragma unroll
    for (int n2 = 0; n2 < 2; ++n2) {
      const int r = wn * 64 + (pair * 2 + n2) * 16 + r16;
      const int sw = (r & 7) << 3;
#pragma unroll
      for (int kc = 0; kc < 2; ++kc)
        bfr[n2][kc] = *(const bf16x8*)&Bs[r * 64 + ((kc * 32 + g4 * 8) ^ sw)];
    }
  };
  auto mmac = [&](int mhalf, int npair) {
#pragma unroll
    for (int i = 0; i < 4; ++i)
#pragma unroll
      for (int n2 = 0; n2 < 2; ++n2)
#pragma unroll
        for (int kc = 0; kc < 2; ++kc)
          acc[mhalf * 4 + i][npair * 2 + n2] = __builtin_amdgcn_mfma_f32_16x16x32_bf16(
              af[mhalf * 4 + i][kc], bfr[n2][kc], acc[mhalf * 4 + i][npair * 2 + n2], 0, 0, 0);
  };

  // prologue: stage tile 0, drain once (template prologue)
  issue(0, 0, 0);
  issue(1, 0, 0);
  issue(2, 0, 0);
  issue(3, 0, 0);
  asm volatile("s_waitcnt vmcnt(0)" ::: "memory");
  __builtin_amdgcn_s_barrier();

  for (int kt2 = 0; kt2 < NT - 1; ++kt2) {
    const int cur = kt2 & 1;
    const u16* As = lds[cur][0];
    const u16* Bs = lds[cur][1];
    const int ktN = (kt2 + 1) * 64;
    // ---- p0: quadrant (mi0-3, ni0-1) ----
    loadA(As, 0);
    loadB(Bs, 0);
    issue(0, cur ^ 1, ktN);
    __builtin_amdgcn_s_barrier();
    asm volatile("s_waitcnt lgkmcnt(0)" ::: "memory");
    asm volatile("s_waitcnt vmcnt(6)" ::: "memory");
    __builtin_amdgcn_sched_barrier(0);
    __builtin_amdgcn_s_setprio(1);
    mmac(0, 0);
    __builtin_amdgcn_s_setprio(0);
    __builtin_amdgcn_s_barrier();
    // ---- p1: (mi4-7, ni0-1) ----
    loadA(As, 1);
    issue(1, cur ^ 1, ktN);
    __builtin_amdgcn_s_barrier();
    asm volatile("s_waitcnt lgkmcnt(0)" ::: "memory");
    asm volatile("s_waitcnt vmcnt(6)" ::: "memory");
    __builtin_amdgcn_sched_barrier(0);
    __builtin_amdgcn_s_setprio(1);
    mmac(1, 0);
    __builtin_amdgcn_s_setprio(0);
    __builtin_amdgcn_s_barrier();
    // ---- p2: (mi4-7, ni2-3) ----
    loadB(Bs, 1);
    issue(2, cur ^ 1, ktN);
    __builtin_amdgcn_s_barrier();
    asm volatile("s_waitcnt lgkmcnt(0)" ::: "memory");
    asm volatile("s_waitcnt vmcnt(6)" ::: "memory");
    __builtin_amdgcn_sched_barrier(0);
    __builtin_amdgcn_s_setprio(1);
    mmac(1, 1);
    __builtin_amdgcn_s_setprio(0);
    __builtin_amdgcn_s_barrier();
    // ---- p3: (mi0-3, ni2-3), no ds_reads ----
    issue(3, cur ^ 1, ktN);
    __builtin_amdgcn_s_barrier();
    __builtin_amdgcn_sched_barrier(0);
    __builtin_amdgcn_s_setprio(1);
    mmac(0, 1);
    __builtin_amdgcn_s_setprio(0);
    __builtin_amdgcn_s_barrier();
  }
  // ---- final tile: drain 4 -> 2 -> 0 ----
  {
    const int cur = (NT - 1) & 1;
    const u16* As = lds[cur][0];
    const u16* Bs = lds[cur][1];
    loadA(As, 0);
    loadB(Bs, 0);
    __builtin_amdgcn_s_barrier();
    asm volatile("s_waitcnt lgkmcnt(0)" ::: "memory");
    asm volatile("s_waitcnt vmcnt(4)" ::: "memory");
    __builtin_amdgcn_sched_barrier(0);
    __builtin_amdgcn_s_setprio(1);
    mmac(0, 0);
    __builtin_amdgcn_s_setprio(0);
    __builtin_amdgcn_s_barrier();
    loadA(As, 1);
    __builtin_amdgcn_s_barrier();
    asm volatile("s_waitcnt lgkmcnt(0)" ::: "memory");
    asm volatile("s_waitcnt vmcnt(2)" ::: "memory");
    __builtin_amdgcn_sched_barrier(0);
    __builtin_amdgcn_s_setprio(1);
    mmac(1, 0);
    __builtin_amdgcn_s_setprio(0);
    __builtin_amdgcn_s_barrier();
    loadB(Bs, 1);
    asm volatile("s_waitcnt lgkmcnt(0)" ::: "memory");
    asm volatile("s_waitcnt vmcnt(0)" ::: "memory");
    __builtin_amdgcn_sched_barrier(0);
    __builtin_amdgcn_s_setprio(1);
    mmac(1, 1);
    mmac(0, 1);
    __builtin_amdgcn_s_setprio(0);
  }

  // epilogue: scatter to q/k/v [B,H,S,D]
  const int which = n0 >> 10;
  u16* dst = which == 0 ? qo : (which == 1 ? ko : vo);
#pragma unroll
  for (int mi = 0; mi < 8; ++mi)
#pragma unroll
    for (int e = 0; e < 4; ++e) {
      const int gr = m0 + wm * 128 + mi * 16 + g4 * 4 + e;
      const int bb = gr >> 11, ss = gr & 2047;
#pragma unroll
      for (int ni = 0; ni < 4; ++ni) {
        const int gc = n0 + wn * 64 + ni * 16 + r16;
        const int hh = (gc >> 6) & 15;
        const int dd = gc & 63;
        dst[(((size_t)bb * H_ + hh) * S_ + ss) * D_ + dd] = f2bf(acc[mi][ni][e]);
      }
    }
}

// ---------------- 2-phase 128x128 GEMM (out-proj + residual) --------------
__global__ __launch_bounds__(256, 2) void gemm_bt1(const u16* __restrict__ A,
                                                   const u16* __restrict__ Bw,
                                                   const int K,
                                                   const float* __restrict__ xres,
                                                   float* __restrict__ outp) {
  __shared__ u16 lds[2][2][128 * 64];
  const int t = threadIdx.x;
  const int lane = t & 63, wv = t >> 6;
  const int wm = wv >> 1, wn = wv & 1;
  const int m0 = blockIdx.y * 128, n0 = blockIdx.x * 128;
  const int r16 = lane & 15, g4 = lane >> 4;

  const f32x4 fzero = {0.f, 0.f, 0.f, 0.f};
  f32x4 acc[4][4];
#pragma unroll
  for (int i = 0; i < 4; ++i)
#pragma unroll
    for (int j = 0; j < 4; ++j) acc[i][j] = fzero;

  const int srow8 = lane >> 3;
  const int scol = (lane & 7) * 8;

  auto stage = [&](int bu, int kt) {
#pragma unroll
    for (int i = 0; i < 4; ++i) {
      const int c = wv * 4 + i;
      const int row = c * 8 + srow8;
      gload16(A + (size_t)(m0 + row) * K + kt + scol, &lds[bu][0][c * 512]);
      gload16(Bw + (size_t)(n0 + row) * K + kt + scol, &lds[bu][1][c * 512]);
    }
  };

  auto compute = [&](int bu) {
    const u16* As = lds[bu][0];
    const u16* Bs = lds[bu][1];
    bf16x8 af[4][2], bfr[4][2];
#pragma unroll
    for (int mi = 0; mi < 4; ++mi)
#pragma unroll
      for (int kc = 0; kc < 2; ++kc)
        af[mi][kc] = *(const bf16x8*)&As[(wm * 64 + mi * 16 + r16) * 64 + kc * 32 + g4 * 8];
#pragma unroll
    for (int ni = 0; ni < 4; ++ni)
#pragma unroll
      for (int kc = 0; kc < 2; ++kc)
        bfr[ni][kc] = *(const bf16x8*)&Bs[(wn * 64 + ni * 16 + r16) * 64 + kc * 32 + g4 * 8];
#pragma unroll
    for (int mi = 0; mi < 4; ++mi)
#pragma unroll
      for (int ni = 0; ni < 4; ++ni)
#pragma unroll
        for (int kc = 0; kc < 2; ++kc)
          acc[mi][ni] = __builtin_amdgcn_mfma_f32_16x16x32_bf16(af[mi][kc], bfr[ni][kc],
                                                                acc[mi][ni], 0, 0, 0);
  };

  stage(0, 0);
  __syncthreads();
  int cur = 0;
  for (int kt = 64; kt < K; kt += 64) {
    stage(cur ^ 1, kt);
    compute(cur);
    __syncthreads();
    cur ^= 1;
  }
  compute(cur);

#pragma unroll
  for (int mi = 0; mi < 4; ++mi)
#pragma unroll
    for (int e = 0; e < 4; ++e) {
      const int gr = m0 + wm * 64 + mi * 16 + g4 * 4 + e;
#pragma unroll
      for (int ni = 0; ni < 4; ++ni) {
        const int gc = n0 + wn * 64 + ni * 16 + r16;
        const size_t idx = (size_t)gr * 1024 + gc;
        outp[idx] = acc[mi][ni][e] + xres[idx];
      }
    }
}

// ---------------- windowed causal flash attention (unchanged) -------------
__global__ __launch_bounds__(256) void attn_kernel(const u16* __restrict__ q,
                                                   const u16* __restrict__ k,
                                                   const u16* __restrict__ v,
                                                   const float* __restrict__ scaler_p,
                                                   u16* __restrict__ ao) {
  __shared__ u16 Qs[64 * 72];
  __shared__ u16 Ks[64 * 72];
  __shared__ u16 Vt[64 * 72];
  __shared__ u16 Ps[4 * 16 * 72];
  const int t = threadIdx.x;
  const int lane = t & 63, wv = t >> 6;
  const int r16 = lane & 15, g4 = lane >> 4;
  const int it = blockIdx.x;
  const int bh = blockIdx.y;
  const int bb = bh >> 4, hh = bh & 15;
  const size_t base = (size_t)bh * (S_ * D_);

  const float tt = 100.f * scaler_p[0];
  const float slope = (tt > 20.f) ? tt : log1pf(expf(tt));
  const float L2E = 1.4426950408889634f;
  const float qs_l2e = 0.125f * L2E;
  const float sl_l2e = slope * L2E;
  int nb = (int)ceilf(80.f / (slope * 64.f));
  if (nb < 1) nb = 1;
  int jt0 = it - nb;
  if (jt0 < 0) jt0 = 0;

  {
    const int r = t >> 2, c = (t & 3) << 4;
    const u16* gp = q + base + (size_t)(it * 64 + r) * D_ + c;
    uint4 a0 = ((const uint4*)gp)[0];
    uint4 a1 = ((const uint4*)gp)[1];
    *(uint4*)&Qs[r * 72 + c] = a0;
    *(uint4*)&Qs[r * 72 + c + 8] = a1;
  }

  float mrun[4] = {-3e38f, -3e38f, -3e38f, -3e38f};
  float lrun[4] = {0.f, 0.f, 0.f, 0.f};
  const f32x4 fzero = {0.f, 0.f, 0.f, 0.f};
  f32x4 oacc[4];
#pragma unroll
  for (int i = 0; i < 4; ++i) oacc[i] = fzero;

  bf16x8 qa[2];
  bool qloaded = false;

  for (int jt = jt0; jt <= it; ++jt) {
    {
      const int r = t >> 2, c = (t & 3) << 4;
      const u16* kg = k + base + (size_t)(jt * 64 + r) * D_ + c;
      uint4 k0 = ((const uint4*)kg)[0];
      uint4 k1 = ((const uint4*)kg)[1];
      *(uint4*)&Ks[r * 72 + c] = k0;
      *(uint4*)&Ks[r * 72 + c + 8] = k1;
      const u16* vg = v + base + (size_t)(jt * 64 + r) * D_ + c;
      union { uint4 u; u16 s[8]; } v0, v1;
      v0.u = ((const uint4*)vg)[0];
      v1.u = ((const uint4*)vg)[1];
#pragma unroll
      for (int j = 0; j < 8; ++j) {
        Vt[(c + j) * 72 + r] = v0.s[j];
        Vt[(c + 8 + j) * 72 + r] = v1.s[j];
      }
    }
    __syncthreads();
    if (!qloaded) {
      qloaded = true;
#pragma unroll
      for (int kc = 0; kc < 2; ++kc)
        qa[kc] = *(const bf16x8*)&Qs[(wv * 16 + r16) * 72 + kc * 32 + g4 * 8];
    }
    f32x4 sfr[4];
#pragma unroll
    for (int nt = 0; nt < 4; ++nt) {
      sfr[nt] = fzero;
#pragma unroll
      for (int kc = 0; kc < 2; ++kc) {
        bf16x8 kb = *(const bf16x8*)&Ks[(nt * 16 + r16) * 72 + kc * 32 + g4 * 8];
        sfr[nt] = __builtin_amdgcn_mfma_f32_16x16x32_bf16(qa[kc], kb, sfr[nt], 0, 0, 0);
      }
    }
    const bool diag = (jt == it);
    const float jb = (float)((jt - it) * 64);
    float pm[4] = {-3e38f, -3e38f, -3e38f, -3e38f};
#pragma unroll
    for (int nt = 0; nt < 4; ++nt) {
      const int jl = nt * 16 + r16;
#pragma unroll
      for (int e = 0; e < 4; ++e) {
        const int il = wv * 16 + g4 * 4 + e;
        float sc = sfr[nt][e] * qs_l2e + sl_l2e * (jb + (float)(jl - il));
        if (diag && jl > il) sc = -3e38f;
        sfr[nt][e] = sc;
        pm[e] = fmaxf(pm[e], sc);
      }
    }
#pragma unroll
    for (int e = 0; e < 4; ++e) {
#pragma unroll
      for (int off = 1; off < 16; off <<= 1) pm[e] = fmaxf(pm[e], __shfl_xor(pm[e], off));
    }
    u16* Psw = Ps + wv * (16 * 72);
    float psum[4] = {0.f, 0.f, 0.f, 0.f};
#pragma unroll
    for (int e = 0; e < 4; ++e) {
      const float mn = fmaxf(mrun[e], pm[e]);
      const float rsc = exp2f(mrun[e] - mn);
      mrun[e] = mn;
      lrun[e] *= rsc;
#pragma unroll
      for (int nt = 0; nt < 4; ++nt) oacc[nt][e] *= rsc;
    }
#pragma unroll
    for (int nt = 0; nt < 4; ++nt)
#pragma unroll
      for (int e = 0; e < 4; ++e) {
        const float p = exp2f(sfr[nt][e] - mrun[e]);
        psum[e] += p;
        Psw[(g4 * 4 + e) * 72 + nt * 16 + r16] = f2bf(p);
      }
#pragma unroll
    for (int e = 0; e < 4; ++e) {
#pragma unroll
      for (int off = 1; off < 16; off <<= 1) psum[e] += __shfl_xor(psum[e], off);
      lrun[e] += psum[e];
    }
    bf16x8 pa[2];
#pragma unroll
    for (int jk = 0; jk < 2; ++jk)
      pa[jk] = *(const bf16x8*)&Psw[r16 * 72 + jk * 32 + g4 * 8];
#pragma unroll
    for (int nt = 0; nt < 4; ++nt)
#pragma unroll
      for (int jk = 0; jk < 2; ++jk) {
        bf16x8 vb = *(const bf16x8*)&Vt[(nt * 16 + r16) * 72 + jk * 32 + g4 * 8];
        oacc[nt] = __builtin_amdgcn_mfma_f32_16x16x32_bf16(pa[jk], vb, oacc[nt], 0, 0, 0);
      }
    __syncthreads();
  }
#pragma unroll
  for (int e = 0; e < 4; ++e) {
    const float inv = 1.f / lrun[e];
    const int row = it * 64 + wv * 16 + g4 * 4 + e;
#pragma unroll
    for (int nt = 0; nt < 4; ++nt) {
      const int col = hh * 64 + nt * 16 + r16;
      ao[((size_t)bb * S_ + row) * E_ + col] = f2bf(oacc[nt][e] * inv);
    }
  }
}

extern "C" void kernel_launch(void* const* d_in, const int* in_sizes, int n_in,
                              void* d_out, int out_size, void* d_ws, size_t ws_size,
                              hipStream_t stream) {
  const float* x = (const float*)d_in[0];
  const float* Wqkv = (const float*)d_in[1];
  const float* Wo = (const float*)d_in[2];
  const float* lnw = (const float*)d_in[3];
  const float* scaler = (const float*)d_in[4];
  float* out = (float*)d_out;
  char* ws = (char*)d_ws;

  u16* xn = (u16*)(ws + 0);
  u16* q = (u16*)(ws + 16777216);
  u16* kk = (u16*)(ws + 33554432);
  u16* vv = (u16*)(ws + 50331648);
  u16* ao = (u16*)(ws + 67108864);
  u16* wqkvb = (u16*)(ws + 83886080);
  u16* wob = (u16*)(ws + 90177536);

  ln_kernel<<<2048, 256, 0, stream>>>(x, lnw, xn);
  cvt_kernel<<<3072, 256, 0, stream>>>(Wqkv, wqkvb);
  cvt_kernel<<<1024, 256, 0, stream>>>(Wo, wob);
  gemm8_qkv<<<dim3(12, 32), 512, 0, stream>>>(xn, wqkvb, q, kk, vv);
  attn_kernel<<<dim3(32, 64), 256, 0, stream>>>(q, kk, vv, scaler, ao);
  gemm_bt1<<<dim3(8, 64), 256, 0, stream>>>(ao, wob, 1024, x, out);
}